// Round 1
// baseline (345.600 us; speedup 1.0000x reference)
//
#include <hip/hip_runtime.h>
#include <hip/hip_fp16.h>
#include <cstdint>
#include <cstddef>

typedef _Float16 f16;
typedef _Float16 f16x8 __attribute__((ext_vector_type(8)));
typedef _Float16 f16x4 __attribute__((ext_vector_type(4)));
typedef float    f32x4 __attribute__((ext_vector_type(4)));

#define MFMA(a, b, c) __builtin_amdgcn_mfma_f32_16x16x32_f16(a, b, c, 0, 0, 0)

// ---------------------------------------------------------------------------
// Problem constants: B=4, S=2048, D=1024, H=16, KS=VS=64, O=1024.
// All four GEMMs are [M=8192, K=1024] x [K=1024, N=1024].
// ---------------------------------------------------------------------------

// LDS swizzles (both-sides; we reg-stage, so write and read use same mapping).
// 64-byte rows (32 fp16): XOR bits 4..5 with row bits 1..2 -> 2-way max.
__device__ __forceinline__ int swzA(int row, int cb) {
    return row * 64 + (cb ^ (((row >> 1) & 3) << 4));
}
// 128-byte rows (64 fp16): XOR bits 4..6 with row bits 0..2 -> 2-way max.
__device__ __forceinline__ int swzK(int row, int cb) {
    return row * 128 + (cb ^ ((row & 7) << 4));
}

// --------------------------- fp32 -> fp16 convert ---------------------------
__global__ void k_convert(const float* __restrict__ src, f16* __restrict__ dst, int n4) {
    int i = blockIdx.x * blockDim.x + threadIdx.x;
    int stride = gridDim.x * blockDim.x;
    for (; i < n4; i += stride) {
        float4 v = ((const float4*)src)[i];
        f16x4 h;
        h[0] = (f16)v.x; h[1] = (f16)v.y; h[2] = (f16)v.z; h[3] = (f16)v.w;
        ((f16x4*)dst)[i] = h;
    }
}

// ------------------- weight transpose + convert to fp16 ---------------------
// mode 0: W is [H=16][D=1024][KS=64] -> Wt[n=h*64+ks][k=d]   (n-major, K contiguous)
// mode 1: W is [K=1024][N=1024]      -> Wt[n][k]
__global__ void k_transpose_w(const float* __restrict__ W, f16* __restrict__ Wt, int mode) {
    int idx = blockIdx.x * blockDim.x + threadIdx.x;
    if (idx >= 1024 * 1024) return;
    int n = idx >> 10, d = idx & 1023;
    float v = (mode == 0) ? W[(n >> 6) * 65536 + d * 64 + (n & 63)]
                          : W[d * 1024 + n];
    Wt[idx] = (f16)v;
}

// ------------------------------- GEMM ---------------------------------------
// C[M=8192][N=1024] = A[M][K=1024] * Bt[N][K]^T + bias[N]
// MODE 0: fp16 store to [M][1024]
// MODE 1: fp16 store transposed for V: addr = (m/2048)*(1024*2048) + n*2048 + m%2048
// MODE 2: fp32 store to [M][1024] (final output)
template <int MODE>
__global__ __launch_bounds__(256) void k_gemm(const f16* __restrict__ A,
                                              const f16* __restrict__ Bt,
                                              const float* __restrict__ bias,
                                              void* __restrict__ Cout) {
    __shared__ char As[128 * 64];
    __shared__ char Bs[128 * 64];
    const int tid = threadIdx.x;
    const int wid = tid >> 6, lane = tid & 63;
    const int wr = wid >> 1, wc = wid & 1;          // 2x2 waves, each 64x64 out
    const int lr = lane & 15, lg = lane >> 4;
    const int row0 = blockIdx.x * 128, col0 = blockIdx.y * 128;

    f32x4 acc[4][4];
#pragma unroll
    for (int m = 0; m < 4; ++m)
#pragma unroll
        for (int n = 0; n < 4; ++n) acc[m][n] = (f32x4){0.f, 0.f, 0.f, 0.f};

    for (int k0 = 0; k0 < 1024; k0 += 32) {
        __syncthreads();
#pragma unroll
        for (int i = 0; i < 2; ++i) {               // stage 128x32 fp16 tiles
            int s = tid + i * 256;                  // 0..511 slots of 16B
            int r = s >> 2, cb = (s & 3) * 16;
            f16x8 va = *(const f16x8*)&A[(size_t)(row0 + r) * 1024 + k0 + (s & 3) * 8];
            f16x8 vb = *(const f16x8*)&Bt[(size_t)(col0 + r) * 1024 + k0 + (s & 3) * 8];
            *(f16x8*)&As[swzA(r, cb)] = va;
            *(f16x8*)&Bs[swzA(r, cb)] = vb;
        }
        __syncthreads();
        f16x8 af[4], bf[4];
#pragma unroll
        for (int m = 0; m < 4; ++m) af[m] = *(const f16x8*)&As[swzA(wr * 64 + m * 16 + lr, lg * 16)];
#pragma unroll
        for (int n = 0; n < 4; ++n) bf[n] = *(const f16x8*)&Bs[swzA(wc * 64 + n * 16 + lr, lg * 16)];
#pragma unroll
        for (int m = 0; m < 4; ++m)
#pragma unroll
            for (int n = 0; n < 4; ++n) acc[m][n] = MFMA(af[m], bf[n], acc[m][n]);
    }

#pragma unroll
    for (int m = 0; m < 4; ++m) {
#pragma unroll
        for (int n = 0; n < 4; ++n) {
            int col = col0 + wc * 64 + n * 16 + lr;
            float bv = bias[col];
#pragma unroll
            for (int r = 0; r < 4; ++r) {
                int row = row0 + wr * 64 + m * 16 + lg * 4 + r;  // C/D: col=lane&15, row=(lane>>4)*4+reg
                float v = acc[m][n][r] + bv;
                if (MODE == 0) {
                    ((f16*)Cout)[(size_t)row * 1024 + col] = (f16)v;
                } else if (MODE == 2) {
                    ((float*)Cout)[(size_t)row * 1024 + col] = v;
                } else {
                    ((f16*)Cout)[(size_t)(row >> 11) * (1024 * 2048) + (size_t)col * 2048 + (row & 2047)] = (f16)v;
                }
            }
        }
    }
}

// ------------------------------ attention -----------------------------------
// grid: (S/64, B*H). 4 waves/block, each wave owns 16 q-rows.
// Swapped QK^T: S^T = mfma(A=K_tile, B=Q^T) so per-q-row softmax stats are
// lane-local after shfl_xor(16/32); O accumulated transposed (O^T[vd][q]).
__global__ __launch_bounds__(256) void k_attn(const f16* __restrict__ q,
                                              const f16* __restrict__ k,
                                              const f16* __restrict__ vT,
                                              f16* __restrict__ cat) {
    const int bh = blockIdx.y;
    const int b = bh >> 4, h = bh & 15;
    const int q0 = blockIdx.x * 64;
    const int tid = threadIdx.x, wid = tid >> 6, lane = tid & 63;
    const int lr = lane & 15, lg = lane >> 4;

    __shared__ char Ks[32 * 128];     // [kpos 0..31][64 f16] swizzled (swzK)
    __shared__ char Vs[64 * 64];      // [vd 0..63][32 f16]  swizzled (swzA)
    __shared__ char Ps[4][16 * 64];   // per-wave P^T: [qrow 0..15][32 f16] swzA

    const int qrow = q0 + wid * 16 + lr;
    const size_t qbase = ((size_t)(b * 2048) + qrow) * 1024 + h * 64;
    const f16x8 qf0 = *(const f16x8*)&q[qbase + lg * 8];
    const f16x8 qf1 = *(const f16x8*)&q[qbase + 32 + lg * 8];

    f32x4 o[4];
#pragma unroll
    for (int m = 0; m < 4; ++m) o[m] = (f32x4){0.f, 0.f, 0.f, 0.f};
    float m_r = -3.0e38f, l_r = 0.f;
    const float SC = 0.125f * 1.44269504089f;  // 1/sqrt(64) folded with log2(e)

    for (int kt = 0; kt < 2048; kt += 32) {
        __syncthreads();
        {   // cooperative stage: K tile 32x64, V^T tile 64x32 (fp16)
            int r = tid >> 3, c = tid & 7;
            *(f16x8*)&Ks[swzK(r, c * 16)] =
                *(const f16x8*)&k[((size_t)(b * 2048 + kt + r)) * 1024 + h * 64 + c * 8];
            int vr = tid >> 2, vc = tid & 3;
            *(f16x8*)&Vs[swzA(vr, vc * 16)] =
                *(const f16x8*)&vT[((size_t)(b * 1024 + h * 64 + vr)) * 2048 + kt + vc * 8];
        }
        __syncthreads();

        // S^T tiles: D[kpos][qrow], kpos tile t covers 16t..16t+15
        f32x4 st[2];
#pragma unroll
        for (int t = 0; t < 2; ++t) {
            f16x8 kf0 = *(const f16x8*)&Ks[swzK(t * 16 + lr, lg * 16)];
            f16x8 kf1 = *(const f16x8*)&Ks[swzK(t * 16 + lr, 64 + lg * 16)];
            f32x4 z = (f32x4){0.f, 0.f, 0.f, 0.f};
            z = MFMA(kf0, qf0, z);
            z = MFMA(kf1, qf1, z);
            st[t] = z;
        }

        // online softmax, stats per q-row (= lane&15), in log2 units
        float tmax = -3.0e38f;
#pragma unroll
        for (int t = 0; t < 2; ++t)
#pragma unroll
            for (int r = 0; r < 4; ++r) tmax = fmaxf(tmax, st[t][r]);
        tmax = fmaxf(tmax, __shfl_xor(tmax, 16, 64));
        tmax = fmaxf(tmax, __shfl_xor(tmax, 32, 64));
        float m_new = fmaxf(m_r, tmax * SC);
        float alpha = exp2f(m_r - m_new);
        float psum = 0.f;
        f16 ph[2][4];
#pragma unroll
        for (int t = 0; t < 2; ++t)
#pragma unroll
            for (int r = 0; r < 4; ++r) {
                float p = exp2f(st[t][r] * SC - m_new);
                psum += p;
                ph[t][r] = (f16)p;
            }
        psum += __shfl_xor(psum, 16, 64);
        psum += __shfl_xor(psum, 32, 64);
        m_r = m_new;
        l_r = l_r * alpha + psum;

        // write P^T to per-wave LDS: Ps[qrow=lr][kpos = t*16 + lg*4 + r]
#pragma unroll
        for (int t = 0; t < 2; ++t) {
            f16x4 pk;
            pk[0] = ph[t][0]; pk[1] = ph[t][1]; pk[2] = ph[t][2]; pk[3] = ph[t][3];
            *(f16x4*)&Ps[wid][swzA(lr, t * 32 + lg * 8)] = pk;
        }

        // rescale O^T (lane-local: O^T col = qrow = lane&15)
#pragma unroll
        for (int m = 0; m < 4; ++m)
#pragma unroll
            for (int r = 0; r < 4; ++r) o[m][r] *= alpha;

        // PV: O^T[vd][q] += V^T[vd][kpos] * P^T[kpos][q]
        f16x8 pf = *(const f16x8*)&Ps[wid][swzA(lr, lg * 16)];
#pragma unroll
        for (int m = 0; m < 4; ++m) {
            f16x8 vf = *(const f16x8*)&Vs[swzA(m * 16 + lr, lg * 16)];
            o[m] = MFMA(vf, pf, o[m]);
        }
    }

    float inv = 1.f / l_r;
    size_t cbase = ((size_t)(b * 2048) + qrow) * 1024 + h * 64 + lg * 4;
#pragma unroll
    for (int m = 0; m < 4; ++m) {
        f16x4 ov;
#pragma unroll
        for (int r = 0; r < 4; ++r) ov[r] = (f16)(o[m][r] * inv);
        *(f16x4*)&cat[cbase + m * 16] = ov;
    }
}

// ---------------------------------------------------------------------------
extern "C" void kernel_launch(void* const* d_in, const int* in_sizes, int n_in,
                              void* d_out, int out_size, void* d_ws, size_t ws_size,
                              hipStream_t stream) {
    const float* Q  = (const float*)d_in[0];
    const float* K  = (const float*)d_in[1];
    const float* V  = (const float*)d_in[2];
    const float* Wq = (const float*)d_in[3];
    const float* bq = (const float*)d_in[4];
    const float* Wk = (const float*)d_in[5];
    const float* bk = (const float*)d_in[6];
    const float* Wv = (const float*)d_in[7];
    const float* bv = (const float*)d_in[8];
    const float* Wo = (const float*)d_in[9];
    const float* bo = (const float*)d_in[10];

    char* ws = (char*)d_ws;
    size_t off = 0;
    auto alloc = [&](size_t bytes) {
        char* p = ws + off;
        off += (bytes + 255) & ~(size_t)255;
        return p;
    };
    f16* Qh  = (f16*)alloc(8192ULL * 1024 * 2);
    f16* Kh  = (f16*)alloc(8192ULL * 1024 * 2);
    f16* Vh  = (f16*)alloc(8192ULL * 1024 * 2);
    f16* WqT = (f16*)alloc(1024ULL * 1024 * 2);
    f16* WkT = (f16*)alloc(1024ULL * 1024 * 2);
    f16* WvT = (f16*)alloc(1024ULL * 1024 * 2);
    f16* WoT = (f16*)alloc(1024ULL * 1024 * 2);
    f16* qb  = (f16*)alloc(8192ULL * 1024 * 2);
    f16* kb  = (f16*)alloc(8192ULL * 1024 * 2);
    f16* vTb = (f16*)alloc(8192ULL * 1024 * 2);  // [B][H][vd][S]
    f16* cat = (f16*)alloc(8192ULL * 1024 * 2);  // [B*S][H*VS]

    k_convert<<<2048, 256, 0, stream>>>(Q, Qh, 8192 * 1024 / 4);
    k_convert<<<2048, 256, 0, stream>>>(K, Kh, 8192 * 1024 / 4);
    k_convert<<<2048, 256, 0, stream>>>(V, Vh, 8192 * 1024 / 4);
    k_transpose_w<<<4096, 256, 0, stream>>>(Wq, WqT, 0);
    k_transpose_w<<<4096, 256, 0, stream>>>(Wk, WkT, 0);
    k_transpose_w<<<4096, 256, 0, stream>>>(Wv, WvT, 0);
    k_transpose_w<<<4096, 256, 0, stream>>>(Wo, WoT, 1);

    dim3 gg(64, 8);
    k_gemm<0><<<gg, 256, 0, stream>>>(Qh, WqT, bq, qb);
    k_gemm<0><<<gg, 256, 0, stream>>>(Kh, WkT, bk, kb);
    k_gemm<1><<<gg, 256, 0, stream>>>(Vh, WvT, bv, vTb);

    k_attn<<<dim3(32, 64), 256, 0, stream>>>(qb, kb, vTb, cat);

    k_gemm<2><<<gg, 256, 0, stream>>>(cat, WoT, bo, d_out);
}